// Round 5
// baseline (337.908 us; speedup 1.0000x reference)
//
#include <hip/hip_runtime.h>

#define NB 4
#define NC 64
#define NH 256
#define NW 256
#define PLANE ((long)NB * NC * NH * NW)   // 16.78M elements per direction
#define HW    ((long)NH * NW)

typedef float vf4 __attribute__((ext_vector_type(4)));

// V4: V3b + float4 vertical with exact XCD pinning.
//  - Vertical: 128 blocks; block b=8i+r handles slabs 16i+r and 16i+8+r
//    (both have s%8 == r == blk%8 -> XCD pin preserved for vertical AND
//    horizontal reuse). Per slab: 64 f4-columns x {down, up} = 2 waves;
//    2 slabs -> 4 full waves/block. f4 halves vector-instruction count vs
//    f2 and tightens the up/down opposite-sweep window for L2 hits.
//  - Horizontal: unchanged from V3b (wave-per-4-rows, fused right+left via
//    shfl composite scan, nontemporal stores, slab-clustered XCD-pinned).
__global__ __launch_bounds__(256) void irnn_fused(
    const float* __restrict__ x,
    const float* __restrict__ w_up,    const float* __restrict__ b_up,
    const float* __restrict__ w_right, const float* __restrict__ b_right,
    const float* __restrict__ w_down,  const float* __restrict__ b_down,
    const float* __restrict__ w_left,  const float* __restrict__ b_left,
    float* __restrict__ out)
{
    const int t   = threadIdx.x;
    const int blk = blockIdx.x;

    if (blk < 128) {
        // -------- vertical scans: block = 2 same-XCD slabs, f4 columns --------
        const int  r   = blk & 7;              // XCD
        const int  i   = blk >> 3;             // 0..15
        const int  s   = (t >= 128 ? 16 * i + 8 + r : 16 * i + r);  // slab
        const int  rr  = t & 127;
        const bool up  = rr >= 64;
        const int  lane = rr & 63;             // f4-column
        const int  c   = s & (NC - 1);
        const long base = (long)s * HW + lane * 4;
        const float wc = up ? w_up[c] : w_down[c];
        const float bb = up ? b_up[c] : b_down[c];
        float* o = out + (up ? 0L : 2L) * PLANE;
        const long stp = up ? -(long)NW : (long)NW;
        long idx = up ? base + (long)(NH - 1) * NW : base;

        vf4 h = *(const vf4*)(x + idx);        // boundary row = raw input
        __builtin_nontemporal_store(h, (vf4*)(o + idx));
        for (int batch = 0; batch < 31; ++batch) {
            vf4 v[8];
            #pragma unroll
            for (int k = 0; k < 8; ++k)
                v[k] = *(const vf4*)(x + idx + (long)(k + 1) * stp);
            #pragma unroll
            for (int k = 0; k < 8; ++k) {
                h.x = fmaxf(wc * h.x + bb + v[k].x, 0.0f);
                h.y = fmaxf(wc * h.y + bb + v[k].y, 0.0f);
                h.z = fmaxf(wc * h.z + bb + v[k].z, 0.0f);
                h.w = fmaxf(wc * h.w + bb + v[k].w, 0.0f);
                __builtin_nontemporal_store(h, (vf4*)(o + idx + (long)(k + 1) * stp));
            }
            idx += 8L * stp;
        }
        vf4 v[7];
        #pragma unroll
        for (int k = 0; k < 7; ++k)
            v[k] = *(const vf4*)(x + idx + (long)(k + 1) * stp);
        #pragma unroll
        for (int k = 0; k < 7; ++k) {
            h.x = fmaxf(wc * h.x + bb + v[k].x, 0.0f);
            h.y = fmaxf(wc * h.y + bb + v[k].y, 0.0f);
            h.z = fmaxf(wc * h.z + bb + v[k].z, 0.0f);
            h.w = fmaxf(wc * h.w + bb + v[k].w, 0.0f);
            __builtin_nontemporal_store(h, (vf4*)(o + idx + (long)(k + 1) * stp));
        }
    } else {
        // -------- horizontal scans (fused right+left, wave per 4 rows) --------
        // hb in [0,4096): s = (hb>>7)*8 + (hb&7)  (blk%8 == s%8, XCD pin);
        // j = (hb&127)>>3 -> 16-row group; 16 blocks/slab per 128-block window.
        const int hb = blk - 128;
        const int s  = ((hb >> 7) << 3) + (hb & 7);   // slab 0..255
        const int j  = (hb & 127) >> 3;               // 0..15
        const int lane = t & 63;
        const int c  = s & (NC - 1);
        const int h0 = j * 16 + (t >> 6) * 4;         // 4 rows per wave
        const float wr = w_right[c], br = b_right[c];
        const float wl = w_left[c],  bl = b_left[c];
        float* oR = out + 1L * PLANE;
        float* oL = out + 3L * PLANE;

        long rowb = (long)s * HW + (long)h0 * NW;
        vf4 v = *(const vf4*)(x + rowb + lane * 4);

        #pragma unroll
        for (int rw = 0; rw < 4; ++rw) {
            vf4 vn = v;
            if (rw < 3) vn = *(const vf4*)(x + rowb + NW + lane * 4); // prefetch

            float cc, mm, dd;
            vf4 r;

            // ---------------- RIGHT (scan toward +w) ----------------
            if (lane == 0) {
                float h = v.x;                      r.x = h;   // w=0: raw input
                h = fmaxf(wr * h + br + v.y, 0.0f); r.y = h;
                h = fmaxf(wr * h + br + v.z, 0.0f); r.z = h;
                h = fmaxf(wr * h + br + v.w, 0.0f); r.w = h;
                cc = h; mm = 0.0f; dd = h;          // constant function: m exactly 0
            } else {
                cc = 0.0f; mm = wr; dd = br + v.x;
                float a;
                a = br + v.y; cc = fmaxf(0.0f, wr * cc + a); dd = wr * dd + a; mm *= wr;
                a = br + v.z; cc = fmaxf(0.0f, wr * cc + a); dd = wr * dd + a; mm *= wr;
                a = br + v.w; cc = fmaxf(0.0f, wr * cc + a); dd = wr * dd + a; mm *= wr;
            }
            #pragma unroll
            for (int off = 1; off < 64; off <<= 1) {
                float pc = __shfl_up(cc, off, 64);
                float pm = __shfl_up(mm, off, 64);
                float pd = __shfl_up(dd, off, 64);
                if (lane >= off) {                  // mine AFTER partner
                    cc = fmaxf(cc, mm * pc + dd);
                    dd = mm * pd + dd;
                    mm = mm * pm;
                }
            }
            {
                float pc = __shfl_up(cc, 1, 64);
                float pd = __shfl_up(dd, 1, 64);
                if (lane > 0) {
                    float h = fmaxf(pc, pd);        // neighbor's m == 0 exactly
                    h = fmaxf(wr * h + br + v.x, 0.0f); r.x = h;
                    h = fmaxf(wr * h + br + v.y, 0.0f); r.y = h;
                    h = fmaxf(wr * h + br + v.z, 0.0f); r.z = h;
                    h = fmaxf(wr * h + br + v.w, 0.0f); r.w = h;
                }
            }
            __builtin_nontemporal_store(r, (vf4*)(oR + rowb + lane * 4));

            // ---------------- LEFT (scan toward -w) ----------------
            if (lane == 63) {
                float h = v.w;                      r.w = h;   // w=255: raw input
                h = fmaxf(wl * h + bl + v.z, 0.0f); r.z = h;
                h = fmaxf(wl * h + bl + v.y, 0.0f); r.y = h;
                h = fmaxf(wl * h + bl + v.x, 0.0f); r.x = h;
                cc = h; mm = 0.0f; dd = h;
            } else {
                cc = 0.0f; mm = wl; dd = bl + v.w;
                float a;
                a = bl + v.z; cc = fmaxf(0.0f, wl * cc + a); dd = wl * dd + a; mm *= wl;
                a = bl + v.y; cc = fmaxf(0.0f, wl * cc + a); dd = wl * dd + a; mm *= wl;
                a = bl + v.x; cc = fmaxf(0.0f, wl * cc + a); dd = wl * dd + a; mm *= wl;
            }
            #pragma unroll
            for (int off = 1; off < 64; off <<= 1) {
                float pc = __shfl_down(cc, off, 64);
                float pm = __shfl_down(mm, off, 64);
                float pd = __shfl_down(dd, off, 64);
                if (lane + off < 64) {
                    cc = fmaxf(cc, mm * pc + dd);
                    dd = mm * pd + dd;
                    mm = mm * pm;
                }
            }
            {
                float pc = __shfl_down(cc, 1, 64);
                float pd = __shfl_down(dd, 1, 64);
                if (lane < 63) {
                    float h = fmaxf(pc, pd);
                    h = fmaxf(wl * h + bl + v.w, 0.0f); r.w = h;
                    h = fmaxf(wl * h + bl + v.z, 0.0f); r.z = h;
                    h = fmaxf(wl * h + bl + v.y, 0.0f); r.y = h;
                    h = fmaxf(wl * h + bl + v.x, 0.0f); r.x = h;
                }
            }
            __builtin_nontemporal_store(r, (vf4*)(oL + rowb + lane * 4));

            rowb += NW;
            v = vn;
        }
    }
}

extern "C" void kernel_launch(void* const* d_in, const int* in_sizes, int n_in,
                              void* d_out, int out_size, void* d_ws, size_t ws_size,
                              hipStream_t stream) {
    const float* x       = (const float*)d_in[0];
    const float* w_up    = (const float*)d_in[1];
    const float* w_right = (const float*)d_in[2];
    const float* w_down  = (const float*)d_in[3];
    const float* w_left  = (const float*)d_in[4];
    const float* b_up    = (const float*)d_in[5];
    const float* b_right = (const float*)d_in[6];
    const float* b_down  = (const float*)d_in[7];
    const float* b_left  = (const float*)d_in[8];
    float* out = (float*)d_out;

    // [0,128): vertical, block = 2 same-XCD slabs (up+down fused, f4)
    // [128,4224): horizontal fused right+left, slab-clustered XCD-pinned
    dim3 grid(128 + 4096);
    irnn_fused<<<grid, 256, 0, stream>>>(
        x, w_up, b_up, w_right, b_right, w_down, b_down, w_left, b_left, out);
}

// Round 6
// 331.573 us; speedup vs baseline: 1.0191x; 1.0191x over previous
//
#include <hip/hip_runtime.h>

#define NB 4
#define NC 64
#define NH 256
#define NW 256
#define PLANE ((long)NB * NC * NH * NW)   // 16.78M elements per direction
#define HW    ((long)NH * NW)

typedef float vf2 __attribute__((ext_vector_type(2)));
typedef float vf4 __attribute__((ext_vector_type(4)));

// V5: consolidate V3b (best measured: 329.8) + memory-level-parallelism bump.
//  - Vertical: V3b layout (block = slab, t<128 down / t>=128 up, f2 columns)
//    with 16-deep load batches (2x outstanding loads vs V3b).
//  - Horizontal: V3b shfl-composite scan, all 4 row loads hoisted to wave
//    start; w==1.0 wave-uniform fast path drops the mm lane of the scan
//    (2 shfls/step instead of 3; bitwise-identical results).
//  - All output stores nontemporal; XCD-pinned slab clustering as V3b.
__global__ __launch_bounds__(256) void irnn_fused(
    const float* __restrict__ x,
    const float* __restrict__ w_up,    const float* __restrict__ b_up,
    const float* __restrict__ w_right, const float* __restrict__ b_right,
    const float* __restrict__ w_down,  const float* __restrict__ b_down,
    const float* __restrict__ w_left,  const float* __restrict__ b_left,
    float* __restrict__ out)
{
    const int t   = threadIdx.x;
    const int blk = blockIdx.x;

    if (blk < 256) {
        // -------- vertical scans: block = slab, fused up+down, f2 cols --------
        const int  s   = blk;                  // slab (b*C + c); XCD = s%8
        const bool up  = t >= 128;
        const int  w2  = (t & 127) << 1;       // f2-column 0,2,..,254
        const int  c   = s & (NC - 1);
        const long base = (long)s * HW + w2;
        const float wc = up ? w_up[c] : w_down[c];
        const float bb = up ? b_up[c] : b_down[c];
        float* o = out + (up ? 0L : 2L) * PLANE;
        const long stp = up ? -(long)NW : (long)NW;
        long idx = up ? base + (long)(NH - 1) * NW : base;

        vf2 h = *(const vf2*)(x + idx);        // boundary row = raw input
        __builtin_nontemporal_store(h, (vf2*)(o + idx));
        // rows 1..240 in 15 batches of 16, then 15-row tail
        for (int batch = 0; batch < 15; ++batch) {
            vf2 v[16];
            #pragma unroll
            for (int k = 0; k < 16; ++k)
                v[k] = *(const vf2*)(x + idx + (long)(k + 1) * stp);
            #pragma unroll
            for (int k = 0; k < 16; ++k) {
                h.x = fmaxf(wc * h.x + bb + v[k].x, 0.0f);
                h.y = fmaxf(wc * h.y + bb + v[k].y, 0.0f);
                __builtin_nontemporal_store(h, (vf2*)(o + idx + (long)(k + 1) * stp));
            }
            idx += 16L * stp;
        }
        vf2 v[15];
        #pragma unroll
        for (int k = 0; k < 15; ++k)
            v[k] = *(const vf2*)(x + idx + (long)(k + 1) * stp);
        #pragma unroll
        for (int k = 0; k < 15; ++k) {
            h.x = fmaxf(wc * h.x + bb + v[k].x, 0.0f);
            h.y = fmaxf(wc * h.y + bb + v[k].y, 0.0f);
            __builtin_nontemporal_store(h, (vf2*)(o + idx + (long)(k + 1) * stp));
        }
    } else {
        // -------- horizontal scans (fused right+left, wave per 4 rows) --------
        // hb in [0,4096): s = (hb>>7)*8 + (hb&7)  (blk%8 == s%8, XCD pin);
        // j = (hb&127)>>3 -> 16-row group; 16 blocks/slab per 128-block window.
        const int hb = blk - 256;
        const int s  = ((hb >> 7) << 3) + (hb & 7);   // slab 0..255
        const int j  = (hb & 127) >> 3;               // 0..15
        const int lane = t & 63;
        const int c  = s & (NC - 1);
        const int h0 = j * 16 + (t >> 6) * 4;         // 4 rows per wave
        const float wr = w_right[c], br = b_right[c];
        const float wl = w_left[c],  bl = b_left[c];
        const bool unit = (wr == 1.0f) & (wl == 1.0f);  // per-channel uniform
        float* oR = out + 1L * PLANE;
        float* oL = out + 3L * PLANE;

        const long rowb0 = (long)s * HW + (long)h0 * NW;
        vf4 vr[4];
        #pragma unroll
        for (int rw = 0; rw < 4; ++rw)        // all 4 rows in flight up front
            vr[rw] = *(const vf4*)(x + rowb0 + (long)rw * NW + lane * 4);

        #pragma unroll
        for (int rw = 0; rw < 4; ++rw) {
            const vf4 v = vr[rw];
            const long rowb = rowb0 + (long)rw * NW;

            float cc, mm, dd;
            vf4 r;

            // ---------------- RIGHT (scan toward +w) ----------------
            if (lane == 0) {
                float h = v.x;                      r.x = h;   // w=0: raw input
                h = fmaxf(wr * h + br + v.y, 0.0f); r.y = h;
                h = fmaxf(wr * h + br + v.z, 0.0f); r.z = h;
                h = fmaxf(wr * h + br + v.w, 0.0f); r.w = h;
                cc = h; mm = 0.0f; dd = h;          // constant function: m exactly 0
            } else {
                cc = 0.0f; mm = wr; dd = br + v.x;
                float a;
                a = br + v.y; cc = fmaxf(0.0f, wr * cc + a); dd = wr * dd + a; mm *= wr;
                a = br + v.z; cc = fmaxf(0.0f, wr * cc + a); dd = wr * dd + a; mm *= wr;
                a = br + v.w; cc = fmaxf(0.0f, wr * cc + a); dd = wr * dd + a; mm *= wr;
            }
            if (unit) {
                // m == 1 everywhere: f(h)=max(c, h+d); drop the mm lane.
                // fma(1,p,d) rounds identically to p+d -> bitwise-same output.
                #pragma unroll
                for (int off = 1; off < 64; off <<= 1) {
                    float pc = __shfl_up(cc, off, 64);
                    float pd = __shfl_up(dd, off, 64);
                    if (lane >= off) {
                        cc = fmaxf(cc, pc + dd);
                        dd = pd + dd;
                    }
                }
            } else {
                #pragma unroll
                for (int off = 1; off < 64; off <<= 1) {
                    float pc = __shfl_up(cc, off, 64);
                    float pm = __shfl_up(mm, off, 64);
                    float pd = __shfl_up(dd, off, 64);
                    if (lane >= off) {              // mine AFTER partner
                        cc = fmaxf(cc, mm * pc + dd);
                        dd = mm * pd + dd;
                        mm = mm * pm;
                    }
                }
            }
            {
                float pc = __shfl_up(cc, 1, 64);
                float pd = __shfl_up(dd, 1, 64);
                if (lane > 0) {
                    float h = fmaxf(pc, pd);        // neighbor's m == 0 exactly
                    h = fmaxf(wr * h + br + v.x, 0.0f); r.x = h;
                    h = fmaxf(wr * h + br + v.y, 0.0f); r.y = h;
                    h = fmaxf(wr * h + br + v.z, 0.0f); r.z = h;
                    h = fmaxf(wr * h + br + v.w, 0.0f); r.w = h;
                }
            }
            __builtin_nontemporal_store(r, (vf4*)(oR + rowb + lane * 4));

            // ---------------- LEFT (scan toward -w) ----------------
            if (lane == 63) {
                float h = v.w;                      r.w = h;   // w=255: raw input
                h = fmaxf(wl * h + bl + v.z, 0.0f); r.z = h;
                h = fmaxf(wl * h + bl + v.y, 0.0f); r.y = h;
                h = fmaxf(wl * h + bl + v.x, 0.0f); r.x = h;
                cc = h; mm = 0.0f; dd = h;
            } else {
                cc = 0.0f; mm = wl; dd = bl + v.w;
                float a;
                a = bl + v.z; cc = fmaxf(0.0f, wl * cc + a); dd = wl * dd + a; mm *= wl;
                a = bl + v.y; cc = fmaxf(0.0f, wl * cc + a); dd = wl * dd + a; mm *= wl;
                a = bl + v.x; cc = fmaxf(0.0f, wl * cc + a); dd = wl * dd + a; mm *= wl;
            }
            if (unit) {
                #pragma unroll
                for (int off = 1; off < 64; off <<= 1) {
                    float pc = __shfl_down(cc, off, 64);
                    float pd = __shfl_down(dd, off, 64);
                    if (lane + off < 64) {
                        cc = fmaxf(cc, pc + dd);
                        dd = pd + dd;
                    }
                }
            } else {
                #pragma unroll
                for (int off = 1; off < 64; off <<= 1) {
                    float pc = __shfl_down(cc, off, 64);
                    float pm = __shfl_down(mm, off, 64);
                    float pd = __shfl_down(dd, off, 64);
                    if (lane + off < 64) {
                        cc = fmaxf(cc, mm * pc + dd);
                        dd = mm * pd + dd;
                        mm = mm * pm;
                    }
                }
            }
            {
                float pc = __shfl_down(cc, 1, 64);
                float pd = __shfl_down(dd, 1, 64);
                if (lane < 63) {
                    float h = fmaxf(pc, pd);
                    h = fmaxf(wl * h + bl + v.w, 0.0f); r.w = h;
                    h = fmaxf(wl * h + bl + v.z, 0.0f); r.z = h;
                    h = fmaxf(wl * h + bl + v.y, 0.0f); r.y = h;
                    h = fmaxf(wl * h + bl + v.x, 0.0f); r.x = h;
                }
            }
            __builtin_nontemporal_store(r, (vf4*)(oL + rowb + lane * 4));
        }
    }
}

extern "C" void kernel_launch(void* const* d_in, const int* in_sizes, int n_in,
                              void* d_out, int out_size, void* d_ws, size_t ws_size,
                              hipStream_t stream) {
    const float* x       = (const float*)d_in[0];
    const float* w_up    = (const float*)d_in[1];
    const float* w_right = (const float*)d_in[2];
    const float* w_down  = (const float*)d_in[3];
    const float* w_left  = (const float*)d_in[4];
    const float* b_up    = (const float*)d_in[5];
    const float* b_right = (const float*)d_in[6];
    const float* b_down  = (const float*)d_in[7];
    const float* b_left  = (const float*)d_in[8];
    float* out = (float*)d_out;

    // [0,256): vertical, block = slab (up+down fused, f2, 16-deep batches)
    // [256,4352): horizontal fused right+left, slab-clustered XCD-pinned
    dim3 grid(256 + 4096);
    irnn_fused<<<grid, 256, 0, stream>>>(
        x, w_up, b_up, w_right, b_right, w_down, b_down, w_left, b_left, out);
}